// Round 1
// baseline (146.066 us; speedup 1.0000x reference)
//
#include <hip/hip_runtime.h>
#include <hip/hip_fp16.h>

typedef _Float16 f16;
typedef _Float16 half8 __attribute__((ext_vector_type(8)));
typedef float f32x4 __attribute__((ext_vector_type(4)));

#define BATCH 8
#define NTOK 2048
#define FIN 256
#define FOUT 256
#define ALPHA 0.2f

// ---------------- K0: W[k][o] fp32 -> WT[o][k] fp16 ----------------
__global__ void k_wt(const float* __restrict__ W, f16* __restrict__ WT) {
    __shared__ float t[32][33];
    int o0 = blockIdx.x * 32, k0 = blockIdx.y * 32;
    int tx = threadIdx.x, ty = threadIdx.y;
    t[ty][tx] = W[(k0 + ty) * FOUT + o0 + tx];
    __syncthreads();
    WT[(o0 + ty) * FIN + (k0 + tx)] = (f16)t[tx][ty];
}

// ---------------- K1: Wh = x @ W, store WhT[b][o][n] fp16 ----------------
// BM=64 rows, BN=256 (full), 4 waves (wave w -> o in [64w,64w+64)), BK=64.
__global__ __launch_bounds__(256) void k_gemm(const float* __restrict__ x,
                                              const f16* __restrict__ WT,
                                              f16* __restrict__ WhT) {
    __shared__ f16 Ah[64][72];    // x tile, fp16, padded
    __shared__ f16 Bt[256][72];   // WT tile [o][k], padded
    int m0 = blockIdx.x * 64;
    int t = threadIdx.x;
    int lane = t & 63, w = t >> 6;
    f32x4 acc[4][4] = {};  // [fi(row16)][fo(col16)]

    for (int k0 = 0; k0 < FIN; k0 += 64) {
        // stage A: thread t -> row t>>2, 16 k's
        {
            int r = t >> 2, c = (t & 3) * 16;
            const float* src = x + (size_t)(m0 + r) * FIN + k0 + c;
            f16 tmp[16];
#pragma unroll
            for (int q = 0; q < 16; q++) tmp[q] = (f16)src[q];
            *(half8*)&Ah[r][c] = *(half8*)&tmp[0];
            *(half8*)&Ah[r][c + 8] = *(half8*)&tmp[8];
        }
        // stage B: thread t -> WT row t, 64 k's
        {
            const f16* src = WT + (size_t)t * FIN + k0;
#pragma unroll
            for (int q = 0; q < 8; q++)
                *(half8*)&Bt[t][q * 8] = *(const half8*)&src[q * 8];
        }
        __syncthreads();
#pragma unroll
        for (int kc = 0; kc < 2; kc++) {
            int krow = kc * 32 + ((lane >> 4) * 8);
            half8 af[4], bf[4];
#pragma unroll
            for (int fi = 0; fi < 4; fi++)
                af[fi] = *(half8*)&Ah[fi * 16 + (lane & 15)][krow];
#pragma unroll
            for (int fo = 0; fo < 4; fo++)
                bf[fo] = *(half8*)&Bt[w * 64 + fo * 16 + (lane & 15)][krow];
#pragma unroll
            for (int fi = 0; fi < 4; fi++)
#pragma unroll
                for (int fo = 0; fo < 4; fo++)
                    acc[fi][fo] = __builtin_amdgcn_mfma_f32_16x16x32_f16(
                        af[fi], bf[fo], acc[fi][fo], 0, 0, 0);
        }
        __syncthreads();
    }
    // store transposed: WhT[b][o][n]
    int b = m0 >> 11;
    int nbase = m0 & (NTOK - 1);
#pragma unroll
    for (int fi = 0; fi < 4; fi++)
#pragma unroll
        for (int fo = 0; fo < 4; fo++) {
            int o = w * 64 + fo * 16 + (lane & 15);
#pragma unroll
            for (int q = 0; q < 4; q++) {
                int n = nbase + fi * 16 + (lane >> 4) * 4 + q;
                WhT[((size_t)b * FOUT + o) * NTOK + n] = (f16)acc[fi][fo][q];
            }
        }
}

// ---------------- K2: s1 = Wh@a1, s2 = Wh@a2 (from WhT) ----------------
__global__ __launch_bounds__(256) void k_s12(const f16* __restrict__ WhT,
                                             const float* __restrict__ a,
                                             float* __restrict__ s1,
                                             float* __restrict__ s2) {
    int b = blockIdx.y;
    int n = blockIdx.x * 256 + threadIdx.x;
    const f16* base = WhT + (size_t)b * FOUT * NTOK + n;
    float a1 = 0.f, a2 = 0.f;
#pragma unroll 4
    for (int o = 0; o < FOUT; o++) {
        float wh = (float)base[(size_t)o * NTOK];
        a1 += wh * a[o];
        a2 += wh * a[FOUT + o];
    }
    s1[b * NTOK + n] = a1;
    s2[b * NTOK + n] = a2;
}

// ---------------- K3: fused masked softmax + P@Wh + ELU ----------------
// block: 256 thr (4 waves), 32 rows. j streamed in tiles of 128.
// wave w owns o-range [64w, 64w+64). thread t: row r=t>>3, cols (t&7)*16..+16.
__global__ __launch_bounds__(256) void k_attn(const int* __restrict__ adj,
                                              const f16* __restrict__ WhT,
                                              const float* __restrict__ s1g,
                                              const float* __restrict__ s2g,
                                              float* __restrict__ out) {
    __shared__ float s2_lds[NTOK];
    __shared__ f16 P[32][136];         // padded: row stride 272B
    __shared__ float scale_lds[32];
    __shared__ float l_lds[32];
    __shared__ float s1_lds[32];

    int b = blockIdx.y;
    int i0 = blockIdx.x * 32;
    int t = threadIdx.x;
    int lane = t & 63, w = t >> 6;

    {
        const float4* src = (const float4*)(s2g + (size_t)b * NTOK);
        float4* dst = (float4*)s2_lds;
        for (int q = t; q < NTOK / 4; q += 256) dst[q] = src[q];
        if (t < 32) s1_lds[t] = s1g[(size_t)b * NTOK + i0 + t];
    }
    __syncthreads();

    int r = t >> 3;
    int c0 = (t & 7) * 16;
    float s1r = s1_lds[r];
    float m = -3.0e38f, l = 0.f;
    f32x4 acc[2][4] = {};
    const int* adjrow = adj + ((size_t)(b * NTOK + i0 + r)) * NTOK;

    for (int j0 = 0; j0 < NTOK; j0 += 128) {
        int ai[16];
        {
            const int4* ap = (const int4*)(adjrow + j0 + c0);
            ((int4*)ai)[0] = ap[0];
            ((int4*)ai)[1] = ap[1];
            ((int4*)ai)[2] = ap[2];
            ((int4*)ai)[3] = ap[3];
        }
        float e[16];
        float lm = -3.0e38f;
#pragma unroll
        for (int q = 0; q < 16; q++) {
            float sum = s1r + s2_lds[j0 + c0 + q];
            float ev = sum > 0.f ? sum : ALPHA * sum;
            e[q] = ev;
            if (ai[q] > 0) lm = fmaxf(lm, ev);
        }
#pragma unroll
        for (int d = 1; d < 8; d <<= 1) lm = fmaxf(lm, __shfl_xor(lm, d));
        float m_new = fmaxf(m, lm);
        float scl = __expf(m - m_new);  // m=-3e38 first time -> 0 (acc is 0 anyway)
        float ts = 0.f;
        f16 ph[16];
#pragma unroll
        for (int q = 0; q < 16; q++) {
            float p = (ai[q] > 0) ? __expf(e[q] - m_new) : 0.f;
            ts += p;
            ph[q] = (f16)p;
        }
#pragma unroll
        for (int d = 1; d < 8; d <<= 1) ts += __shfl_xor(ts, d);
        l = l * scl + ts;
        m = m_new;
        *(half8*)&P[r][c0] = *(half8*)&ph[0];
        *(half8*)&P[r][c0 + 8] = *(half8*)&ph[8];
        if ((t & 7) == 0) scale_lds[r] = scl;
        __syncthreads();

        // rescale accumulators by this tile's per-row scale
#pragma unroll
        for (int fi = 0; fi < 2; fi++) {
            f32x4 s4 = *(f32x4*)&scale_lds[fi * 16 + (lane >> 4) * 4];
#pragma unroll
            for (int fo = 0; fo < 4; fo++) acc[fi][fo] *= s4;
        }
        // P(32x128) @ Wh(128x256): A from LDS, B straight from WhT (L2-resident)
#pragma unroll
        for (int kc = 0; kc < 4; kc++) {
            int koff = kc * 32 + (lane >> 4) * 8;
            half8 af0 = *(half8*)&P[(lane & 15)][koff];
            half8 af1 = *(half8*)&P[16 + (lane & 15)][koff];
#pragma unroll
            for (int fo = 0; fo < 4; fo++) {
                const half8* bp = (const half8*)(WhT +
                    ((size_t)b * FOUT + w * 64 + fo * 16 + (lane & 15)) * NTOK +
                    j0 + koff);
                half8 bf = *bp;
                acc[0][fo] = __builtin_amdgcn_mfma_f32_16x16x32_f16(af0, bf, acc[0][fo], 0, 0, 0);
                acc[1][fo] = __builtin_amdgcn_mfma_f32_16x16x32_f16(af1, bf, acc[1][fo], 0, 0, 0);
            }
        }
        __syncthreads();
    }

    if ((t & 7) == 0) l_lds[r] = l;
    __syncthreads();

#pragma unroll
    for (int fi = 0; fi < 2; fi++) {
        f32x4 l4 = *(f32x4*)&l_lds[fi * 16 + (lane >> 4) * 4];
#pragma unroll
        for (int fo = 0; fo < 4; fo++) {
            int o = w * 64 + fo * 16 + (lane & 15);
#pragma unroll
            for (int q = 0; q < 4; q++) {
                float v = acc[fi][fo][q] / l4[q];
                v = v > 0.f ? v : __expf(v) - 1.f;
                int i = i0 + fi * 16 + (lane >> 4) * 4 + q;
                out[((size_t)b * NTOK + i) * FOUT + o] = v;
            }
        }
    }
}

extern "C" void kernel_launch(void* const* d_in, const int* in_sizes, int n_in,
                              void* d_out, int out_size, void* d_ws, size_t ws_size,
                              hipStream_t stream) {
    const float* x = (const float*)d_in[0];
    const int* adj = (const int*)d_in[1];
    const float* W = (const float*)d_in[2];
    const float* a = (const float*)d_in[3];
    float* out = (float*)d_out;

    char* ws = (char*)d_ws;
    f16* WT = (f16*)ws;                                   // 128 KB
    f16* WhT = (f16*)(ws + (128 << 10));                  // 8 MB
    float* s1 = (float*)(ws + (128 << 10) + (8 << 20));   // 64 KB
    float* s2 = s1 + BATCH * NTOK;                        // 64 KB

    k_wt<<<dim3(FOUT / 32, FIN / 32), dim3(32, 32), 0, stream>>>(W, WT);
    k_gemm<<<dim3(BATCH * NTOK / 64), 256, 0, stream>>>(x, WT, WhT);
    k_s12<<<dim3(NTOK / 256, BATCH), 256, 0, stream>>>(WhT, a, s1, s2);
    k_attn<<<dim3(NTOK / 32, BATCH), 256, 0, stream>>>(adj, WhT, s1, s2, out);
}

// Round 2
// 123.538 us; speedup vs baseline: 1.1824x; 1.1824x over previous
//
#include <hip/hip_runtime.h>
#include <hip/hip_fp16.h>

typedef _Float16 f16;
typedef _Float16 half8 __attribute__((ext_vector_type(8)));
typedef float f32x4 __attribute__((ext_vector_type(4)));

#define BATCH 8
#define NTOK 2048
#define FIN 256
#define FOUT 256
#define ALPHA 0.2f

// ---------------- K0: W[k][o] fp32 -> WT[o][k] fp16 ----------------
__global__ void k_wt(const float* __restrict__ W, f16* __restrict__ WT) {
    __shared__ float t[32][33];
    int o0 = blockIdx.x * 32, k0 = blockIdx.y * 32;
    int tx = threadIdx.x, ty = threadIdx.y;
    t[ty][tx] = W[(k0 + ty) * FOUT + o0 + tx];
    __syncthreads();
    WT[(o0 + ty) * FIN + (k0 + tx)] = (f16)t[tx][ty];
}

// ---------------- K1: Wh = x @ W, store WhT[b][o][n] fp16 ----------------
__global__ __launch_bounds__(256) void k_gemm(const float* __restrict__ x,
                                              const f16* __restrict__ WT,
                                              f16* __restrict__ WhT) {
    __shared__ f16 Ah[64][72];
    __shared__ f16 Bt[256][72];
    int m0 = blockIdx.x * 64;
    int t = threadIdx.x;
    int lane = t & 63, w = t >> 6;
    f32x4 acc[4][4] = {};

    for (int k0 = 0; k0 < FIN; k0 += 64) {
        {
            int r = t >> 2, c = (t & 3) * 16;
            const float* src = x + (size_t)(m0 + r) * FIN + k0 + c;
            f16 tmp[16];
#pragma unroll
            for (int q = 0; q < 16; q++) tmp[q] = (f16)src[q];
            *(half8*)&Ah[r][c] = *(half8*)&tmp[0];
            *(half8*)&Ah[r][c + 8] = *(half8*)&tmp[8];
        }
        {
            const f16* src = WT + (size_t)t * FIN + k0;
#pragma unroll
            for (int q = 0; q < 8; q++)
                *(half8*)&Bt[t][q * 8] = *(const half8*)&src[q * 8];
        }
        __syncthreads();
#pragma unroll
        for (int kc = 0; kc < 2; kc++) {
            int krow = kc * 32 + ((lane >> 4) * 8);
            half8 af[4], bf[4];
#pragma unroll
            for (int fi = 0; fi < 4; fi++)
                af[fi] = *(half8*)&Ah[fi * 16 + (lane & 15)][krow];
#pragma unroll
            for (int fo = 0; fo < 4; fo++)
                bf[fo] = *(half8*)&Bt[w * 64 + fo * 16 + (lane & 15)][krow];
#pragma unroll
            for (int fi = 0; fi < 4; fi++)
#pragma unroll
                for (int fo = 0; fo < 4; fo++)
                    acc[fi][fo] = __builtin_amdgcn_mfma_f32_16x16x32_f16(
                        af[fi], bf[fo], acc[fi][fo], 0, 0, 0);
        }
        __syncthreads();
    }
    int b = m0 >> 11;
    int nbase = m0 & (NTOK - 1);
#pragma unroll
    for (int fi = 0; fi < 4; fi++)
#pragma unroll
        for (int fo = 0; fo < 4; fo++) {
            int o = w * 64 + fo * 16 + (lane & 15);
#pragma unroll
            for (int q = 0; q < 4; q++) {
                int n = nbase + fi * 16 + (lane >> 4) * 4 + q;
                WhT[((size_t)b * FOUT + o) * NTOK + n] = (f16)acc[fi][fo][q];
            }
        }
}

// ---------------- K2: s1 = Wh@a1, s2 = Wh@a2 (from WhT) ----------------
__global__ __launch_bounds__(256) void k_s12(const f16* __restrict__ WhT,
                                             const float* __restrict__ a,
                                             float* __restrict__ s1,
                                             float* __restrict__ s2) {
    int b = blockIdx.y;
    int n = blockIdx.x * 256 + threadIdx.x;
    const f16* base = WhT + (size_t)b * FOUT * NTOK + n;
    float a1 = 0.f, a2 = 0.f;
#pragma unroll 4
    for (int o = 0; o < FOUT; o++) {
        float wh = (float)base[(size_t)o * NTOK];
        a1 += wh * a[o];
        a2 += wh * a[FOUT + o];
    }
    s1[b * NTOK + n] = a1;
    s2[b * NTOK + n] = a2;
}

// ---------------- K3: fused masked softmax + P@Wh + ELU ----------------
// 512 thr = 8 waves = 2 j-groups x 4 o-waves. 32 rows/block.
// Each j-group: online softmax over its 1024-j half (8 tiles of 128),
// adj register-double-buffered, P LDS double-buffered (1 barrier/iter).
// Flash combine of the two groups in LDS at the end.
__global__ __launch_bounds__(512) void k_attn(const int* __restrict__ adj,
                                              const f16* __restrict__ WhT,
                                              const float* __restrict__ s1g,
                                              const float* __restrict__ s2g,
                                              float* __restrict__ out) {
    __shared__ float s2_lds[NTOK];
    __shared__ f16 P[2][2][32][136];        // [jg][buf][row][k] padded
    __shared__ float scale_lds[2][2][32];   // [jg][buf][row]
    __shared__ float m_lds[2][32];
    __shared__ float l_lds[2][32];
    __shared__ float s1_lds[32];

    int b = blockIdx.y;
    int i0 = blockIdx.x * 32;
    int t = threadIdx.x;
    int lane = t & 63;
    int w = t >> 6;
    int ow = w & 3;
    int jg = w >> 2;       // j-group (also == t>>8)
    int tg = t & 255;      // thread id within group

    {
        const float4* src = (const float4*)(s2g + (size_t)b * NTOK);
        float4* dst = (float4*)s2_lds;
        int q = t;                      // NTOK/4 == 512 == blockDim
        dst[q] = src[q];
        if (t < 32) s1_lds[t] = s1g[(size_t)b * NTOK + i0 + t];
    }
    __syncthreads();

    int r = tg >> 3;
    int c0 = (tg & 7) * 16;
    float s1r = s1_lds[r];
    float m = -3.0e38f, l = 0.f;
    f32x4 acc[2][4] = {};
    const int* adjrow = adj + ((size_t)(b * NTOK + i0 + r)) * NTOK + jg * 1024 + c0;

    int4 nxt0, nxt1, nxt2, nxt3;
    {
        const int4* ap = (const int4*)adjrow;
        nxt0 = ap[0]; nxt1 = ap[1]; nxt2 = ap[2]; nxt3 = ap[3];
    }

    for (int jt = 0; jt < 8; jt++) {
        int ai[16];
        ((int4*)ai)[0] = nxt0; ((int4*)ai)[1] = nxt1;
        ((int4*)ai)[2] = nxt2; ((int4*)ai)[3] = nxt3;
        if (jt < 7) {
            const int4* ap = (const int4*)(adjrow + (jt + 1) * 128);
            nxt0 = ap[0]; nxt1 = ap[1]; nxt2 = ap[2]; nxt3 = ap[3];
        }
        int buf = jt & 1;
        int jbase = jg * 1024 + jt * 128;

        float e[16];
        float lm = -3.0e38f;
#pragma unroll
        for (int q = 0; q < 16; q++) {
            float sum = s1r + s2_lds[jbase + c0 + q];
            float ev = sum > 0.f ? sum : ALPHA * sum;
            e[q] = ev;
            if (ai[q] > 0) lm = fmaxf(lm, ev);
        }
#pragma unroll
        for (int d = 1; d < 8; d <<= 1) lm = fmaxf(lm, __shfl_xor(lm, d));
        float m_new = fmaxf(m, lm);
        float scl = __expf(m - m_new);
        float ts = 0.f;
        f16 ph[16];
#pragma unroll
        for (int q = 0; q < 16; q++) {
            float p = (ai[q] > 0) ? __expf(e[q] - m_new) : 0.f;
            ts += p;
            ph[q] = (f16)p;
        }
#pragma unroll
        for (int d = 1; d < 8; d <<= 1) ts += __shfl_xor(ts, d);
        l = l * scl + ts;
        m = m_new;
        *(half8*)&P[jg][buf][r][c0] = *(half8*)&ph[0];
        *(half8*)&P[jg][buf][r][c0 + 8] = *(half8*)&ph[8];
        if ((tg & 7) == 0) scale_lds[jg][buf][r] = scl;
        __syncthreads();

#pragma unroll
        for (int fi = 0; fi < 2; fi++) {
            f32x4 s4 = *(f32x4*)&scale_lds[jg][buf][fi * 16 + (lane >> 4) * 4];
#pragma unroll
            for (int fo = 0; fo < 4; fo++) acc[fi][fo] *= s4;
        }
#pragma unroll
        for (int kc = 0; kc < 4; kc++) {
            int koff = kc * 32 + (lane >> 4) * 8;
            half8 af0 = *(half8*)&P[jg][buf][(lane & 15)][koff];
            half8 af1 = *(half8*)&P[jg][buf][16 + (lane & 15)][koff];
#pragma unroll
            for (int fo = 0; fo < 4; fo++) {
                const half8* bp = (const half8*)(WhT +
                    ((size_t)b * FOUT + ow * 64 + fo * 16 + (lane & 15)) * NTOK +
                    jbase + koff);
                half8 bf = *bp;
                acc[0][fo] = __builtin_amdgcn_mfma_f32_16x16x32_f16(af0, bf, acc[0][fo], 0, 0, 0);
                acc[1][fo] = __builtin_amdgcn_mfma_f32_16x16x32_f16(af1, bf, acc[1][fo], 0, 0, 0);
            }
        }
    }

    if ((tg & 7) == 0) { m_lds[jg][r] = m; l_lds[jg][r] = l; }
    __syncthreads();

    // flash combine of the two j-groups, staged through LDS (reuses P space)
    float (*accx)[260] = (float (*)[260])&P[0][0][0][0];   // 32 x 260 fp32

    if (jg == 1) {
#pragma unroll
        for (int fi = 0; fi < 2; fi++)
#pragma unroll
            for (int q = 0; q < 4; q++) {
                int row = fi * 16 + (lane >> 4) * 4 + q;
                float m0v = m_lds[0][row], m1v = m_lds[1][row];
                float mt = fmaxf(m0v, m1v);
                float f1 = __expf(m1v - mt);
#pragma unroll
                for (int fo = 0; fo < 4; fo++) {
                    int o = ow * 64 + fo * 16 + (lane & 15);
                    accx[row][o + (o >> 6)] = acc[fi][fo][q] * f1;  // mild skew
                }
            }
    }
    __syncthreads();

    if (jg == 0) {
#pragma unroll
        for (int fi = 0; fi < 2; fi++)
#pragma unroll
            for (int q = 0; q < 4; q++) {
                int row = fi * 16 + (lane >> 4) * 4 + q;
                float m0v = m_lds[0][row], m1v = m_lds[1][row];
                float mt = fmaxf(m0v, m1v);
                float f0 = __expf(m0v - mt);
                float f1 = __expf(m1v - mt);
                float lt = l_lds[0][row] * f0 + l_lds[1][row] * f1;
#pragma unroll
                for (int fo = 0; fo < 4; fo++) {
                    int o = ow * 64 + fo * 16 + (lane & 15);
                    float v = (acc[fi][fo][q] * f0 + accx[row][o + (o >> 6)]) / lt;
                    v = v > 0.f ? v : __expf(v) - 1.f;
                    int i = i0 + row;
                    out[((size_t)b * NTOK + i) * FOUT + o] = v;
                }
            }
    }
}

extern "C" void kernel_launch(void* const* d_in, const int* in_sizes, int n_in,
                              void* d_out, int out_size, void* d_ws, size_t ws_size,
                              hipStream_t stream) {
    const float* x = (const float*)d_in[0];
    const int* adj = (const int*)d_in[1];
    const float* W = (const float*)d_in[2];
    const float* a = (const float*)d_in[3];
    float* out = (float*)d_out;

    char* ws = (char*)d_ws;
    f16* WT = (f16*)ws;                                   // 128 KB
    f16* WhT = (f16*)(ws + (128 << 10));                  // 8 MB
    float* s1 = (float*)(ws + (128 << 10) + (8 << 20));   // 64 KB
    float* s2 = s1 + BATCH * NTOK;                        // 64 KB

    k_wt<<<dim3(FOUT / 32, FIN / 32), dim3(32, 32), 0, stream>>>(W, WT);
    k_gemm<<<dim3(BATCH * NTOK / 64), 256, 0, stream>>>(x, WT, WhT);
    k_s12<<<dim3(NTOK / 256, BATCH), 256, 0, stream>>>(WhT, a, s1, s2);
    k_attn<<<dim3(NTOK / 32, BATCH), 512, 0, stream>>>(adj, WhT, s1, s2, out);
}

// Round 3
// 118.182 us; speedup vs baseline: 1.2359x; 1.0453x over previous
//
#include <hip/hip_runtime.h>
#include <hip/hip_fp16.h>

typedef _Float16 f16;
typedef _Float16 half8 __attribute__((ext_vector_type(8)));
typedef float f32x4 __attribute__((ext_vector_type(4)));

#define BATCH 8
#define NTOK 2048
#define FIN 256
#define FOUT 256
#define ALPHA 0.2f
#define WHS 2080   // WhT row stride in elements (pad breaks 4KB stride)

// ---------------- K0: W[k][o] fp32 -> WT[o][k] fp16 ----------------
__global__ void k_wt(const float* __restrict__ W, f16* __restrict__ WT) {
    __shared__ float t[32][33];
    int o0 = blockIdx.x * 32, k0 = blockIdx.y * 32;
    int tx = threadIdx.x, ty = threadIdx.y;
    t[ty][tx] = W[(k0 + ty) * FOUT + o0 + tx];
    __syncthreads();
    WT[(o0 + ty) * FIN + (k0 + tx)] = (f16)t[tx][ty];
}

// ---------------- K pack: adj int32 -> bitmask (1 bit per edge) ----------------
// Each wave handles 256 consecutive ints per chunk: 4 coalesced scalar loads + 4 ballots.
__global__ __launch_bounds__(256) void k_pack(const int* __restrict__ adj,
                                              unsigned long long* __restrict__ mask) {
    int lane = threadIdx.x & 63;
    size_t wv = (((size_t)blockIdx.x * 256 + threadIdx.x) >> 6);
    for (int it = 0; it < 8; it++) {
        size_t wave = wv + (size_t)it * 16384;
        const int* base = adj + wave * 256;
        unsigned long long m0 = __ballot(base[lane] > 0);
        unsigned long long m1 = __ballot(base[64 + lane] > 0);
        unsigned long long m2 = __ballot(base[128 + lane] > 0);
        unsigned long long m3 = __ballot(base[192 + lane] > 0);
        if (lane < 4) {
            unsigned long long v = lane == 0 ? m0 : lane == 1 ? m1 : lane == 2 ? m2 : m3;
            mask[wave * 4 + lane] = v;
        }
    }
}

// ---------------- K1: Wh = x @ W, store WhT[b][o][n] fp16 (stride WHS) ----------------
__global__ __launch_bounds__(256) void k_gemm(const float* __restrict__ x,
                                              const f16* __restrict__ WT,
                                              f16* __restrict__ WhT) {
    __shared__ f16 Ah[64][72];
    __shared__ f16 Bt[256][72];
    int m0 = blockIdx.x * 64;
    int t = threadIdx.x;
    int lane = t & 63, w = t >> 6;
    f32x4 acc[4][4] = {};

    for (int k0 = 0; k0 < FIN; k0 += 64) {
        {
            int r = t >> 2, c = (t & 3) * 16;
            const float* src = x + (size_t)(m0 + r) * FIN + k0 + c;
            f16 tmp[16];
#pragma unroll
            for (int q = 0; q < 16; q++) tmp[q] = (f16)src[q];
            *(half8*)&Ah[r][c] = *(half8*)&tmp[0];
            *(half8*)&Ah[r][c + 8] = *(half8*)&tmp[8];
        }
        {
            const f16* src = WT + (size_t)t * FIN + k0;
#pragma unroll
            for (int q = 0; q < 8; q++)
                *(half8*)&Bt[t][q * 8] = *(const half8*)&src[q * 8];
        }
        __syncthreads();
#pragma unroll
        for (int kc = 0; kc < 2; kc++) {
            int krow = kc * 32 + ((lane >> 4) * 8);
            half8 af[4], bf[4];
#pragma unroll
            for (int fi = 0; fi < 4; fi++)
                af[fi] = *(half8*)&Ah[fi * 16 + (lane & 15)][krow];
#pragma unroll
            for (int fo = 0; fo < 4; fo++)
                bf[fo] = *(half8*)&Bt[w * 64 + fo * 16 + (lane & 15)][krow];
#pragma unroll
            for (int fi = 0; fi < 4; fi++)
#pragma unroll
                for (int fo = 0; fo < 4; fo++)
                    acc[fi][fo] = __builtin_amdgcn_mfma_f32_16x16x32_f16(
                        af[fi], bf[fo], acc[fi][fo], 0, 0, 0);
        }
        __syncthreads();
    }
    int b = m0 >> 11;
    int nbase = m0 & (NTOK - 1);
#pragma unroll
    for (int fi = 0; fi < 4; fi++)
#pragma unroll
        for (int fo = 0; fo < 4; fo++) {
            int o = w * 64 + fo * 16 + (lane & 15);
#pragma unroll
            for (int q = 0; q < 4; q++) {
                int n = nbase + fi * 16 + (lane >> 4) * 4 + q;
                WhT[((size_t)b * FOUT + o) * WHS + n] = (f16)acc[fi][fo][q];
            }
        }
}

// ---------------- K2: s1 = Wh@a1, s2 = Wh@a2 (from WhT) ----------------
__global__ __launch_bounds__(256) void k_s12(const f16* __restrict__ WhT,
                                             const float* __restrict__ a,
                                             float* __restrict__ s1,
                                             float* __restrict__ s2) {
    int b = blockIdx.y;
    int n = blockIdx.x * 256 + threadIdx.x;
    const f16* base = WhT + (size_t)b * FOUT * WHS + n;
    float a1 = 0.f, a2 = 0.f;
#pragma unroll 4
    for (int o = 0; o < FOUT; o++) {
        float wh = (float)base[(size_t)o * WHS];
        a1 += wh * a[o];
        a2 += wh * a[FOUT + o];
    }
    s1[b * NTOK + n] = a1;
    s2[b * NTOK + n] = a2;
}

// ---------------- K3: fused masked softmax + P@Wh + ELU ----------------
// 256 thr = 4 o-waves, 32 rows/block, 16 j-tiles of 128.
// bf[4][4] B-fragments register-staged before softmax (latency hides under VALU);
// P double-buffered in LDS -> single barrier per iteration.
// Grid: linear 512, bid&7 = batch (XCD-pinned: one batch's WhT per XCD L2).
__global__ __launch_bounds__(256, 3) void k_attn(const unsigned* __restrict__ mask,
                                                 const f16* __restrict__ WhT,
                                                 const float* __restrict__ s1g,
                                                 const float* __restrict__ s2g,
                                                 float* __restrict__ out) {
    __shared__ float s2_lds[NTOK];
    __shared__ f16 P[2][32][136];
    __shared__ float scale_lds[2][32];
    __shared__ float l_lds[32];
    __shared__ float s1_lds[32];

    int b = blockIdx.x & 7;
    int i0 = (blockIdx.x >> 3) * 32;
    int t = threadIdx.x;
    int lane = t & 63, ow = t >> 6;

    {
        const float4* src = (const float4*)(s2g + (size_t)b * NTOK);
        float4* dst = (float4*)s2_lds;
        dst[t] = src[t];
        dst[t + 256] = src[t + 256];
        if (t < 32) s1_lds[t] = s1g[(size_t)b * NTOK + i0 + t];
    }
    __syncthreads();

    int r = t >> 3;
    int c0 = (t & 7) * 16;
    float s1r = s1_lds[r];
    float m = -3.0e38f, l = 0.f;
    f32x4 acc[2][4] = {};

    const unsigned* mrow = mask + ((size_t)(b * NTOK + i0 + r)) * 64 + (c0 >> 5);
    int sh = c0 & 16;
    unsigned um_next = mrow[0];

    const f16* wrow[4];
#pragma unroll
    for (int fo = 0; fo < 4; fo++)
        wrow[fo] = WhT + (size_t)(b * FOUT + ow * 64 + fo * 16 + (lane & 15)) * WHS +
                   (lane >> 4) * 8;

    for (int jt = 0; jt < 16; jt++) {
        unsigned um = um_next;
        if (jt < 15) um_next = mrow[(jt + 1) * 4];

        // issue all 16 B-fragment loads up front (independent of softmax)
        half8 bf[4][4];
#pragma unroll
        for (int kc = 0; kc < 4; kc++)
#pragma unroll
            for (int fo = 0; fo < 4; fo++)
                bf[kc][fo] = *(const half8*)(wrow[fo] + jt * 128 + kc * 32);

        unsigned bits = um >> sh;
        float e[16];
        float lm = -3.0e38f;
#pragma unroll
        for (int q = 0; q < 16; q++) {
            float sum = s1r + s2_lds[jt * 128 + c0 + q];
            float ev = sum > 0.f ? sum : ALPHA * sum;
            e[q] = ev;
            if ((bits >> q) & 1) lm = fmaxf(lm, ev);
        }
#pragma unroll
        for (int d = 1; d < 8; d <<= 1) lm = fmaxf(lm, __shfl_xor(lm, d));
        float m_new = fmaxf(m, lm);
        float scl = __expf(m - m_new);
        float ts = 0.f;
        f16 ph[16];
#pragma unroll
        for (int q = 0; q < 16; q++) {
            float p = ((bits >> q) & 1) ? __expf(e[q] - m_new) : 0.f;
            ts += p;
            ph[q] = (f16)p;
        }
#pragma unroll
        for (int d = 1; d < 8; d <<= 1) ts += __shfl_xor(ts, d);
        l = l * scl + ts;
        m = m_new;
        int buf = jt & 1;
        *(half8*)&P[buf][r][c0] = *(half8*)&ph[0];
        *(half8*)&P[buf][r][c0 + 8] = *(half8*)&ph[8];
        if ((t & 7) == 0) scale_lds[buf][r] = scl;
        __syncthreads();

#pragma unroll
        for (int fi = 0; fi < 2; fi++) {
            f32x4 s4 = *(f32x4*)&scale_lds[buf][fi * 16 + (lane >> 4) * 4];
#pragma unroll
            for (int fo = 0; fo < 4; fo++) acc[fi][fo] *= s4;
        }
#pragma unroll
        for (int kc = 0; kc < 4; kc++) {
            int koff = kc * 32 + (lane >> 4) * 8;
            half8 af0 = *(half8*)&P[buf][(lane & 15)][koff];
            half8 af1 = *(half8*)&P[buf][16 + (lane & 15)][koff];
#pragma unroll
            for (int fo = 0; fo < 4; fo++) {
                acc[0][fo] = __builtin_amdgcn_mfma_f32_16x16x32_f16(af0, bf[kc][fo], acc[0][fo], 0, 0, 0);
                acc[1][fo] = __builtin_amdgcn_mfma_f32_16x16x32_f16(af1, bf[kc][fo], acc[1][fo], 0, 0, 0);
            }
        }
        // no trailing barrier: P is double-buffered; next iter's barrier orders reuse
    }

    if ((t & 7) == 0) l_lds[r] = l;
    __syncthreads();

#pragma unroll
    for (int fi = 0; fi < 2; fi++) {
        f32x4 l4 = *(f32x4*)&l_lds[fi * 16 + (lane >> 4) * 4];
#pragma unroll
        for (int fo = 0; fo < 4; fo++) {
            int o = ow * 64 + fo * 16 + (lane & 15);
#pragma unroll
            for (int q = 0; q < 4; q++) {
                float v = acc[fi][fo][q] / l4[q];
                v = v > 0.f ? v : __expf(v) - 1.f;
                int i = i0 + fi * 16 + (lane >> 4) * 4 + q;
                out[((size_t)b * NTOK + i) * FOUT + o] = v;
            }
        }
    }
}

extern "C" void kernel_launch(void* const* d_in, const int* in_sizes, int n_in,
                              void* d_out, int out_size, void* d_ws, size_t ws_size,
                              hipStream_t stream) {
    const float* x = (const float*)d_in[0];
    const int* adj = (const int*)d_in[1];
    const float* W = (const float*)d_in[2];
    const float* a = (const float*)d_in[3];
    float* out = (float*)d_out;

    char* ws = (char*)d_ws;
    f16* WT = (f16*)ws;                                     // 128 KB
    f16* WhT = (f16*)(ws + 131072);                         // 8.13 MB (2048 x 2080 f16)
    float* s1 = (float*)(ws + 131072 + 8519680);            // 64 KB
    float* s2 = s1 + BATCH * NTOK;                          // 64 KB
    unsigned long long* mask64 =
        (unsigned long long*)(ws + 131072 + 8519680 + 131072);  // 4 MB

    k_wt<<<dim3(FOUT / 32, FIN / 32), dim3(32, 32), 0, stream>>>(W, WT);
    k_gemm<<<dim3(BATCH * NTOK / 64), 256, 0, stream>>>(x, WT, WhT);
    k_s12<<<dim3(NTOK / 256, BATCH), 256, 0, stream>>>(WhT, a, s1, s2);
    k_pack<<<dim3(4096), 256, 0, stream>>>(adj, mask64);
    k_attn<<<dim3(BATCH * NTOK / 32), 256, 0, stream>>>((const unsigned*)mask64, WhT, s1, s2, out);
}